// Round 9
// baseline (281.366 us; speedup 1.0000x reference)
//
#include <hip/hip_runtime.h>
#include <math.h>

#define N_NODES 50000
#define N_EDGES 800000
#define F_IN_DIM 128
#define HID 64
#define NG 512
#define NEG 0.2f
#define CAP 64                       // bucket capacity per node
#define SGRID (N_EDGES / 256)        // 3125 scatter blocks, 1 edge/thread
#define GGRID ((N_NODES + 63) / 64)  // 782 gemm blocks

static __device__ __forceinline__ float wave_sum(float v) {
    for (int o = 32; o; o >>= 1) v += __shfl_xor(v, o, 64);
    return v;
}

// bf16 pack/unpack (RNE)
static __device__ __forceinline__ unsigned short f2bf(float f) {
    union { float f; unsigned u; } v; v.f = f;
    unsigned r = (v.u + 0x7FFF + ((v.u >> 16) & 1)) >> 16;
    return (unsigned short)r;
}
static __device__ __forceinline__ float bf2f(unsigned short b) {
    union { unsigned u; float f; } v; v.u = ((unsigned)b) << 16;
    return v.f;
}

// ---- FUSED: bucket build (blocks 0..SGRID) + layer-1 GEMM (blocks SGRID..) ----
// De-sliced scatter: one thread per edge, coalesced loads, zero redundant fetch.
// (XCD slicing removed: round-7 showed atomic XCD-locality buys nothing, and the
// slicing cost 8x redundant dst fetch = ~22MB HBM + 8x filter VALU.)
__global__ __launch_bounds__(256) void scatter_gemm1_k(
        const int* __restrict__ ei, const float* __restrict__ ew,
        int* __restrict__ deg, unsigned* __restrict__ bucket,
        uint2* __restrict__ ovf, int* __restrict__ ovf_cnt,
        float* __restrict__ mean_acc,
        const float* __restrict__ We1, const float* __restrict__ ae1,
        const float* __restrict__ We2, const float* __restrict__ ae2,
        const float* __restrict__ We3, const float* __restrict__ ae3,
        float* __restrict__ ce,
        const float* __restrict__ X, const float* __restrict__ W,
        const float* __restrict__ as_, const float* __restrict__ ad_,
        unsigned short* __restrict__ H, float* __restrict__ Asrc,
        float* __restrict__ Adst) {
    extern __shared__ float smem[];
    const int tid = threadIdx.x;

    if (blockIdx.x < SGRID) {
        // ---------------- scatter path: 1 edge / thread ----------------
        int e = (blockIdx.x << 8) + tid;          // e < 800000 exactly
        int dst = ei[N_EDGES + e];
        int src = ei[e];
        float w = ew[e];
        int pos = atomicAdd(&deg[dst], 1);
        unsigned entry = (unsigned)(src & 0xFFFF) | ((unsigned)f2bf(w) << 16);
        if (pos < CAP) bucket[(dst << 6) + pos] = entry;
        else { int op = atomicAdd(ovf_cnt, 1); ovf[op] = make_uint2((unsigned)dst, entry); }

        int lane = tid & 63, wv = tid >> 6;
        float s = wave_sum(w);
        if (lane == 0) smem[wv] = s;
        __syncthreads();
        if (tid == 0) atomicAdd(mean_acc, smem[0] + smem[1] + smem[2] + smem[3]);

        if (blockIdx.x == 0 && wv >= 1) {
            const float* We = (wv == 1) ? We1 : (wv == 2) ? We2 : We3;
            const float* ae = (wv == 1) ? ae1 : (wv == 2) ? ae2 : ae3;
            float v = We[lane] * ae[lane];
            v = wave_sum(v);
            if (lane == 0) ce[wv - 1] = v;
        }
        return;
    }

    // ---------------- gemm path (layer 1, F = 128) ----------------
    float* Xs = smem;              // 64*17 floats
    float* Wt = smem + 64 * 17;    // 16*64 floats (current k-tile)
    const int tx = tid & 15, ty = tid >> 4;
    const int bid = blockIdx.x - SGRID;
    const int rowBase = bid * 64;

    float4 acc0 = {0,0,0,0}, acc1 = {0,0,0,0}, acc2 = {0,0,0,0}, acc3 = {0,0,0,0};
    const int xrow = tid >> 2;
    const int xkq  = tid & 3;
    const float4* W4 = (const float4*)W;
    float4* Wt4 = (float4*)Wt;

    #pragma unroll 2
    for (int kt = 0; kt < (F_IN_DIM >> 4); ++kt) {
        __syncthreads();
        int k0 = kt << 4;
        int grow = rowBase + xrow;
        float4 xv = {0,0,0,0};
        if (grow < N_NODES)
            xv = *(const float4*)(X + (size_t)grow * F_IN_DIM + k0 + (xkq << 2));
        float* xd = Xs + xrow * 17 + (xkq << 2);
        xd[0] = xv.x; xd[1] = xv.y; xd[2] = xv.z; xd[3] = xv.w;
        Wt4[tid] = W4[(kt << 8) + tid];   // 16x64 tile, one float4/thread
        __syncthreads();

        #pragma unroll
        for (int kk = 0; kk < 16; ++kk) {
            float4 b = *(const float4*)&Wt[kk * HID + (tx << 2)];
            float a0 = Xs[(ty * 4 + 0) * 17 + kk];
            float a1 = Xs[(ty * 4 + 1) * 17 + kk];
            float a2 = Xs[(ty * 4 + 2) * 17 + kk];
            float a3 = Xs[(ty * 4 + 3) * 17 + kk];
            acc0.x += a0 * b.x; acc0.y += a0 * b.y; acc0.z += a0 * b.z; acc0.w += a0 * b.w;
            acc1.x += a1 * b.x; acc1.y += a1 * b.y; acc1.z += a1 * b.z; acc1.w += a1 * b.w;
            acc2.x += a2 * b.x; acc2.y += a2 * b.y; acc2.z += a2 * b.z; acc2.w += a2 * b.w;
            acc3.x += a3 * b.x; acc3.y += a3 * b.y; acc3.z += a3 * b.z; acc3.w += a3 * b.w;
        }
    }

    float4 as4 = *(const float4*)(as_ + (tx << 2));
    float4 ad4 = *(const float4*)(ad_ + (tx << 2));
    float4 accs[4] = {acc0, acc1, acc2, acc3};
    #pragma unroll
    for (int i = 0; i < 4; ++i) {
        int row = rowBase + ty * 4 + i;
        if (row >= N_NODES) break;
        float4 a = accs[i];
        ushort4 hv;
        hv.x = f2bf(a.x); hv.y = f2bf(a.y); hv.z = f2bf(a.z); hv.w = f2bf(a.w);
        *(ushort4*)(H + (size_t)row * HID + (tx << 2)) = hv;
        float vs = a.x * as4.x + a.y * as4.y + a.z * as4.z + a.w * as4.w;
        float vd = a.x * ad4.x + a.y * ad4.y + a.z * ad4.z + a.w * ad4.w;
        #pragma unroll
        for (int o = 8; o; o >>= 1) { vs += __shfl_xor(vs, o, 64); vd += __shfl_xor(vd, o, 64); }
        if (tx == 0) { Asrc[row] = vs; Adst[row] = vd; }
    }
}

#define GATHA(sv0, sv1)                                                         \
    a0 = *(const ushort4*)(H + (size_t)(sv0).x * HID + (qlane << 2));           \
    a1 = *(const ushort4*)(H + (size_t)(sv0).y * HID + (qlane << 2));           \
    a2 = *(const ushort4*)(H + (size_t)(sv0).z * HID + (qlane << 2));           \
    a3 = *(const ushort4*)(H + (size_t)(sv0).w * HID + (qlane << 2));           \
    a4 = *(const ushort4*)(H + (size_t)(sv1).x * HID + (qlane << 2));           \
    a5 = *(const ushort4*)(H + (size_t)(sv1).y * HID + (qlane << 2));           \
    a6 = *(const ushort4*)(H + (size_t)(sv1).z * HID + (qlane << 2));           \
    a7 = *(const ushort4*)(H + (size_t)(sv1).w * HID + (qlane << 2));

#define GATHB(sv0, sv1)                                                         \
    b0 = *(const ushort4*)(H + (size_t)(sv0).x * HID + (qlane << 2));           \
    b1 = *(const ushort4*)(H + (size_t)(sv0).y * HID + (qlane << 2));           \
    b2 = *(const ushort4*)(H + (size_t)(sv0).z * HID + (qlane << 2));           \
    b3 = *(const ushort4*)(H + (size_t)(sv0).w * HID + (qlane << 2));           \
    b4 = *(const ushort4*)(H + (size_t)(sv1).x * HID + (qlane << 2));           \
    b5 = *(const ushort4*)(H + (size_t)(sv1).y * HID + (qlane << 2));           \
    b6 = *(const ushort4*)(H + (size_t)(sv1).z * HID + (qlane << 2));           \
    b7 = *(const ushort4*)(H + (size_t)(sv1).w * HID + (qlane << 2));

#define ACCA(pv0, pv1, ACC)                                                     \
    ACC.x += (pv0).x*bf2f(a0.x) + (pv0).y*bf2f(a1.x) + (pv0).z*bf2f(a2.x) + (pv0).w*bf2f(a3.x) \
           + (pv1).x*bf2f(a4.x) + (pv1).y*bf2f(a5.x) + (pv1).z*bf2f(a6.x) + (pv1).w*bf2f(a7.x); \
    ACC.y += (pv0).x*bf2f(a0.y) + (pv0).y*bf2f(a1.y) + (pv0).z*bf2f(a2.y) + (pv0).w*bf2f(a3.y) \
           + (pv1).x*bf2f(a4.y) + (pv1).y*bf2f(a5.y) + (pv1).z*bf2f(a6.y) + (pv1).w*bf2f(a7.y); \
    ACC.z += (pv0).x*bf2f(a0.z) + (pv0).y*bf2f(a1.z) + (pv0).z*bf2f(a2.z) + (pv0).w*bf2f(a3.z) \
           + (pv1).x*bf2f(a4.z) + (pv1).y*bf2f(a5.z) + (pv1).z*bf2f(a6.z) + (pv1).w*bf2f(a7.z); \
    ACC.w += (pv0).x*bf2f(a0.w) + (pv0).y*bf2f(a1.w) + (pv0).z*bf2f(a2.w) + (pv0).w*bf2f(a3.w) \
           + (pv1).x*bf2f(a4.w) + (pv1).y*bf2f(a5.w) + (pv1).z*bf2f(a6.w) + (pv1).w*bf2f(a7.w);

// Aggregate phase: prefetch-overlapped pipeline (measured-best form).
#define AGG_PHASE(ACC, DENOM)                                                   \
    {                                                                           \
        float a_self = Asrc[n] + ad + c * mv;                                   \
        a_self = (a_self > 0.f) ? a_self : NEG * a_self;                        \
        p_self = __expf(a_self);                                                \
        if (deg <= CAP) {                                                       \
            unsigned eent[4];                                                   \
            _Pragma("unroll")                                                   \
            for (int t = 0; t < 4; ++t) {                                       \
                int j = qlane + (t << 4);                                       \
                unsigned e = (j < deg) ? bucket[start + j] : 0u;                \
                eent[t] = e;                                                    \
                ls[slot][j] = (int)(e & 0xFFFF);                                \
            }                                                                   \
            __builtin_amdgcn_wave_barrier();                                    \
            int4 sA0 = *(int4*)&ls[slot][0];                                    \
            int4 sA1 = *(int4*)&ls[slot][4];                                    \
            ushort4 a0, a1, a2, a3, a4, a5, a6, a7;                             \
            ushort4 b0, b1, b2, b3, b4, b5, b6, b7;                             \
            GATHA(sA0, sA1)                       /* chunk 0 in flight */       \
            rr = *(const ushort4*)(H + (size_t)n * HID + (qlane << 2));         \
            float lsum = 0.f;                                                   \
            _Pragma("unroll")                                                   \
            for (int t = 0; t < 4; ++t) {                                       \
                int j = qlane + (t << 4);                                       \
                float p = 0.f;                                                  \
                if (j < deg) {                                                  \
                    int s = (int)(eent[t] & 0xFFFF);                            \
                    float a = Asrc[s] + ad + c * bf2f((unsigned short)(eent[t] >> 16)); \
                    a = (a > 0.f) ? a : NEG * a;                                \
                    p = __expf(a);                                              \
                    lsum += p;                                                  \
                }                                                               \
                lp[slot][j] = p;                                                \
            }                                                                   \
            if (qlane == 0) lsum += p_self;                                     \
            _Pragma("unroll")                                                   \
            for (int o = 1; o < 16; o <<= 1) lsum += __shfl_xor(lsum, o, 64);   \
            DENOM = lsum;                                                       \
            __builtin_amdgcn_wave_barrier();                                    \
            int dpad = (deg + 7) & ~7;                                          \
            for (int j = 0; j < dpad; j += 8) {                                 \
                int jn = (j + 8 < dpad) ? j + 8 : j;                            \
                int4 t0 = *(int4*)&ls[slot][jn];                                \
                int4 t1 = *(int4*)&ls[slot][jn + 4];                            \
                GATHB(t0, t1)                     /* next chunk in flight */    \
                float4 p0 = *(float4*)&lp[slot][j];                             \
                float4 p1 = *(float4*)&lp[slot][j + 4];                         \
                ACCA(p0, p1, ACC)                                               \
                a0 = b0; a1 = b1; a2 = b2; a3 = b3;                             \
                a4 = b4; a5 = b5; a6 = b6; a7 = b7;                             \
            }                                                                   \
        } else {                                                                \
            int novf = *ovf_cnt_p;                                              \
            float lsum = 0.f;                                                   \
            _Pragma("unroll")                                                   \
            for (int t = 0; t < 4; ++t) {                                       \
                int j = qlane + (t << 4);                                       \
                unsigned e = bucket[start + j];                                 \
                int s = e & 0xFFFF;                                             \
                float a = Asrc[s] + ad + c * bf2f((unsigned short)(e >> 16));   \
                a = (a > 0.f) ? a : NEG * a;                                    \
                float p = __expf(a);                                            \
                lsum += p;                                                      \
                lp[slot][j] = p;                                                \
                ls[slot][j] = s;                                                \
            }                                                                   \
            __builtin_amdgcn_wave_barrier();                                    \
            ushort4 a0, a1, a2, a3, a4, a5, a6, a7;                             \
            for (int j = 0; j < 64; j += 8) {                                   \
                float4 p0 = *(float4*)&lp[slot][j];                             \
                float4 p1 = *(float4*)&lp[slot][j + 4];                         \
                int4 s0 = *(int4*)&ls[slot][j];                                 \
                int4 s1 = *(int4*)&ls[slot][j + 4];                             \
                GATHA(s0, s1)                                                   \
                ACCA(p0, p1, ACC)                                               \
            }                                                                   \
            for (int i = 0; i < novf; ++i) {                                    \
                uint2 o = ovf[i];                                               \
                if ((int)o.x == n) {                                            \
                    unsigned e = o.y;                                           \
                    int s = e & 0xFFFF;                                         \
                    float a = Asrc[s] + ad + c * bf2f((unsigned short)(e >> 16));\
                    a = (a > 0.f) ? a : NEG * a;                                \
                    float p = __expf(a);                                        \
                    if (qlane == 0) lsum += p;                                  \
                    ushort4 r = *(const ushort4*)(H + (size_t)s * HID + (qlane << 2)); \
                    ACC.x += p * bf2f(r.x); ACC.y += p * bf2f(r.y);             \
                    ACC.z += p * bf2f(r.z); ACC.w += p * bf2f(r.w);             \
                }                                                               \
            }                                                                   \
            if (qlane == 0) lsum += p_self;                                     \
            _Pragma("unroll")                                                   \
            for (int o = 1; o < 16; o <<= 1) lsum += __shfl_xor(lsum, o, 64);   \
            DENOM = lsum;                                                       \
            rr = *(const ushort4*)(H + (size_t)n * HID + (qlane << 2));         \
        }                                                                       \
        ACC.x += p_self * bf2f(rr.x); ACC.y += p_self * bf2f(rr.y);             \
        ACC.z += p_self * bf2f(rr.z); ACC.w += p_self * bf2f(rr.w);             \
    }

// ---- FUSED aggregate (layer i) + relu + GEMM (layer i+1) + att dots ----
// Grid = 3125 blocks x 16 nodes: n < N_NODES always (no early return; barrier-safe).
__global__ __launch_bounds__(256) void agg_gemm_k(
        const unsigned short* __restrict__ H, const int* __restrict__ degArr,
        const unsigned* __restrict__ bucket,
        const uint2* __restrict__ ovf, const int* __restrict__ ovf_cnt_p,
        const float* __restrict__ Asrc, const float* __restrict__ Adst,
        const float* __restrict__ ceArr, int ci,
        const float* __restrict__ mean_acc,
        const float* __restrict__ bias,
        const float* __restrict__ Wn, const float* __restrict__ asn,
        const float* __restrict__ adn,
        unsigned short* __restrict__ H2, float* __restrict__ Asrc2,
        float* __restrict__ Adst2) {
    __shared__ float lp[16][64];
    __shared__ int   ls[16][64];
    __shared__ float Wl[64 * 64];      // 16 KB: next-layer weights
    __shared__ float rowBuf[16][68];   // padded rows (272 B stride, 16B-aligned)
    const int tid = threadIdx.x;
    int wv = tid >> 6, lane = tid & 63;
    int qid = lane >> 4, qlane = lane & 15;
    int slot = wv * 4 + qid;
    int n = blockIdx.x * 16 + slot;

    {   // stage next-layer W into LDS (covered by the syncthreads below)
        const float4* W4 = (const float4*)Wn;
        float4* Wl4 = (float4*)Wl;
        for (int i = tid; i < (HID * HID) >> 2; i += 256) Wl4[i] = W4[i];
    }

    int deg = degArr[n];
    int start = n << 6;
    float c = ceArr[ci];
    float ad = Adst[n];
    float mv = mean_acc[0] * (1.0f / (float)N_EDGES);
    float4 acc = {0, 0, 0, 0};
    float denom, p_self;
    ushort4 rr;

    AGG_PHASE(acc, denom)

    // bias + relu (fused layers always relu), stage row for gemm
    float inv = 1.f / (denom + 1e-16f);
    float4 b4 = *(const float4*)(bias + (qlane << 2));
    acc.x = fmaxf(acc.x * inv + b4.x, 0.f);
    acc.y = fmaxf(acc.y * inv + b4.y, 0.f);
    acc.z = fmaxf(acc.z * inv + b4.z, 0.f);
    acc.w = fmaxf(acc.w * inv + b4.w, 0.f);
    *(float4*)&rowBuf[slot][qlane << 2] = acc;
    __syncthreads();

    // gemm: h2[qlane*4..+3] = rowBuf[slot][:] @ Wl
    float4 h2 = {0, 0, 0, 0};
    #pragma unroll
    for (int k4 = 0; k4 < 16; ++k4) {
        float4 a4 = *(const float4*)&rowBuf[slot][k4 << 2];
        const float* wb = &Wl[(k4 << 2) * HID + (qlane << 2)];
        float4 w0 = *(const float4*)(wb);
        float4 w1 = *(const float4*)(wb + HID);
        float4 w2 = *(const float4*)(wb + 2 * HID);
        float4 w3 = *(const float4*)(wb + 3 * HID);
        h2.x += a4.x*w0.x + a4.y*w1.x + a4.z*w2.x + a4.w*w3.x;
        h2.y += a4.x*w0.y + a4.y*w1.y + a4.z*w2.y + a4.w*w3.y;
        h2.z += a4.x*w0.z + a4.y*w1.z + a4.z*w2.z + a4.w*w3.z;
        h2.w += a4.x*w0.w + a4.y*w1.w + a4.z*w2.w + a4.w*w3.w;
    }

    ushort4 hv;
    hv.x = f2bf(h2.x); hv.y = f2bf(h2.y); hv.z = f2bf(h2.z); hv.w = f2bf(h2.w);
    *(ushort4*)(H2 + (size_t)n * HID + (qlane << 2)) = hv;

    float4 as4 = *(const float4*)(asn + (qlane << 2));
    float4 ad4 = *(const float4*)(adn + (qlane << 2));
    float vs = h2.x * as4.x + h2.y * as4.y + h2.z * as4.z + h2.w * as4.w;
    float vd = h2.x * ad4.x + h2.y * ad4.y + h2.z * ad4.z + h2.w * ad4.w;
    #pragma unroll
    for (int o = 8; o; o >>= 1) { vs += __shfl_xor(vs, o, 64); vd += __shfl_xor(vd, o, 64); }
    if (qlane == 0) { Asrc2[n] = vs; Adst2[n] = vd; }
}

// ---- final aggregate (layer 3): emits per-node pooled-readout scalar ----
__global__ __launch_bounds__(256) void aggregate_scalar_k(
        const unsigned short* __restrict__ H, const int* __restrict__ degArr,
        const unsigned* __restrict__ bucket,
        const uint2* __restrict__ ovf, const int* __restrict__ ovf_cnt_p,
        const float* __restrict__ Asrc, const float* __restrict__ Adst,
        const float* __restrict__ ceArr, int ci,
        const float* __restrict__ mean_acc,
        const float* __restrict__ bias, const float* __restrict__ lin_w,
        float* __restrict__ Sout) {
    __shared__ float lp[16][64];
    __shared__ int   ls[16][64];
    int wv = threadIdx.x >> 6, lane = threadIdx.x & 63;
    int qid = lane >> 4, qlane = lane & 15;
    int slot = wv * 4 + qid;
    int n = blockIdx.x * 16 + slot;
    if (n >= N_NODES) return;
    int deg = degArr[n];
    int start = n << 6;
    float c = ceArr[ci];
    float ad = Adst[n];
    float mv = mean_acc[0] * (1.0f / (float)N_EDGES);
    float4 acc = {0, 0, 0, 0};
    float denom, p_self;
    ushort4 rr;

    AGG_PHASE(acc, denom)

    float inv = 1.f / (denom + 1e-16f);
    float4 b4 = *(const float4*)(bias + (qlane << 2));
    float4 lw = *(const float4*)(lin_w + (qlane << 2));
    float s = (acc.x * inv + b4.x) * lw.x
            + (acc.y * inv + b4.y) * lw.y
            + (acc.z * inv + b4.z) * lw.z
            + (acc.w * inv + b4.w) * lw.w;
    #pragma unroll
    for (int o = 8; o; o >>= 1) s += __shfl_xor(s, o, 64);
    if (qlane == 0) Sout[n] = s;
}

// ---- pool + readout over per-node scalars: one wave per group ----
__global__ __launch_bounds__(256) void pool_readout_k(
        const float* __restrict__ S, const int* __restrict__ batch,
        const float* __restrict__ lin_b, float* __restrict__ out) {
    int wv = threadIdx.x >> 6, lane = threadIdx.x & 63;
    int g = blockIdx.x * 4 + wv;
    if (g >= NG) return;
    int lo = 0, hi = N_NODES;
    while (lo < hi) { int m = (lo + hi) >> 1; if (batch[m] < g) lo = m + 1; else hi = m; }
    int start = lo;
    hi = N_NODES;
    while (lo < hi) { int m = (lo + hi) >> 1; if (batch[m] < g + 1) lo = m + 1; else hi = m; }
    int end = lo;
    float acc = 0.f;
    for (int n = start + lane; n < end; n += 64) acc += S[n];
    acc = wave_sum(acc);
    if (lane == 0) {
        float cntf = (float)(end - start);
        float z = acc / fmaxf(cntf, 1.f) + lin_b[0];
        out[g] = 1.f / (1.f + __expf(-z));
    }
}

extern "C" void kernel_launch(void* const* d_in, const int* in_sizes, int n_in,
                              void* d_out, int out_size, void* d_ws, size_t ws_size,
                              hipStream_t stream) {
    const float* x     = (const float*)d_in[0];
    const int*   ei    = (const int*)d_in[1];
    const float* ew    = (const float*)d_in[2];
    const int*   batch = (const int*)d_in[3];
    const float* W1  = (const float*)d_in[4];
    const float* as1 = (const float*)d_in[5];
    const float* ad1 = (const float*)d_in[6];
    const float* We1 = (const float*)d_in[7];
    const float* ae1 = (const float*)d_in[8];
    const float* b1  = (const float*)d_in[9];
    const float* W2  = (const float*)d_in[10];
    const float* as2 = (const float*)d_in[11];
    const float* ad2 = (const float*)d_in[12];
    const float* We2 = (const float*)d_in[13];
    const float* ae2 = (const float*)d_in[14];
    const float* b2  = (const float*)d_in[15];
    const float* W3  = (const float*)d_in[16];
    const float* as3 = (const float*)d_in[17];
    const float* ad3 = (const float*)d_in[18];
    const float* We3 = (const float*)d_in[19];
    const float* ae3 = (const float*)d_in[20];
    const float* b3  = (const float*)d_in[21];
    const float* lin_w = (const float*)d_in[22];
    const float* lin_b = (const float*)d_in[23];
    float* out = (float*)d_out;

    char* w = (char*)d_ws;
    size_t off = 0;
    auto alloc = [&](size_t bytes) -> void* {
        void* p = w + off;
        off = (off + bytes + 255) & ~(size_t)255;
        return p;
    };
    // zeroed region (memset each call; ws is poisoned)
    int*   deg      = (int*)alloc(N_NODES * sizeof(int));
    float* mean_acc = (float*)alloc(sizeof(float));
    int*   ovf_cnt  = (int*)alloc(sizeof(int));
    size_t zero_bytes = off;
    // non-zeroed
    float* ce      = (float*)alloc(4 * sizeof(float));
    unsigned* bucket = (unsigned*)alloc((size_t)N_NODES * CAP * sizeof(unsigned));
    uint2* ovf     = (uint2*)alloc((size_t)N_EDGES * sizeof(uint2));
    float* a_src   = (float*)alloc(N_NODES * sizeof(float));
    float* a_dst   = (float*)alloc(N_NODES * sizeof(float));
    float* a_src2  = (float*)alloc(N_NODES * sizeof(float));
    float* a_dst2  = (float*)alloc(N_NODES * sizeof(float));
    unsigned short* hbuf  = (unsigned short*)alloc((size_t)N_NODES * HID * sizeof(unsigned short));
    unsigned short* hbuf2 = (unsigned short*)alloc((size_t)N_NODES * HID * sizeof(unsigned short));
    float* Sbuf    = (float*)alloc(N_NODES * sizeof(float));

    hipMemsetAsync(d_ws, 0, zero_bytes, stream);

    int agrid = (N_NODES + 15) / 16;   // 3125 -> exactly 50000 nodes
    size_t lds_f = (size_t)(64 * 17 + 16 * 64) * sizeof(float);   // 8.4 KB

    // K1: bucket build + layer-1 GEMM (independent work, one launch)
    scatter_gemm1_k<<<SGRID + GGRID, 256, lds_f, stream>>>(
        ei, ew, deg, bucket, ovf, ovf_cnt, mean_acc,
        We1, ae1, We2, ae2, We3, ae3, ce,
        x, W1, as1, ad1, hbuf, a_src, a_dst);

    // K2: aggregate layer 1 + relu + GEMM layer 2 (H: hbuf -> hbuf2)
    agg_gemm_k<<<agrid, 256, 0, stream>>>(hbuf, deg, bucket, ovf, ovf_cnt,
                                          a_src, a_dst, ce, 0, mean_acc, b1,
                                          W2, as2, ad2, hbuf2, a_src2, a_dst2);

    // K3: aggregate layer 2 + relu + GEMM layer 3 (H: hbuf2 -> hbuf)
    agg_gemm_k<<<agrid, 256, 0, stream>>>(hbuf2, deg, bucket, ovf, ovf_cnt,
                                          a_src2, a_dst2, ce, 1, mean_acc, b2,
                                          W3, as3, ad3, hbuf, a_src, a_dst);

    // K4: aggregate layer 3, fold lin_w dot -> per-node scalar
    aggregate_scalar_k<<<agrid, 256, 0, stream>>>(hbuf, deg, bucket, ovf, ovf_cnt,
                                                  a_src, a_dst, ce, 2, mean_acc,
                                                  b3, lin_w, Sbuf);

    // K5: pool + readout over scalars
    pool_readout_k<<<NG / 4, 256, 0, stream>>>(Sbuf, batch, lin_b, out);
}

// Round 11
// 257.509 us; speedup vs baseline: 1.0926x; 1.0926x over previous
//
#include <hip/hip_runtime.h>
#include <math.h>

#define N_NODES 50000
#define N_EDGES 800000
#define F_IN_DIM 128
#define HID 64
#define NG 512
#define NEG 0.2f
#define CAP 64                       // bucket capacity per node
#define EPB 2048                     // edges per scatter block (8/thread)
#define SGRID ((N_EDGES + EPB - 1) / EPB)   // 391 scatter blocks
#define GGRID ((N_NODES + 63) / 64)  // 782 gemm blocks

static __device__ __forceinline__ float wave_sum(float v) {
    for (int o = 32; o; o >>= 1) v += __shfl_xor(v, o, 64);
    return v;
}

// bf16 pack/unpack (RNE)
static __device__ __forceinline__ unsigned short f2bf(float f) {
    union { float f; unsigned u; } v; v.f = f;
    unsigned r = (v.u + 0x7FFF + ((v.u >> 16) & 1)) >> 16;
    return (unsigned short)r;
}
static __device__ __forceinline__ float bf2f(unsigned short b) {
    union { unsigned u; float f; } v; v.u = ((unsigned)b) << 16;
    return v.f;
}

// ---- FUSED: bucket build (blocks 0..SGRID) + layer-1 GEMM (blocks SGRID..) ----
// Single-pass scatter (no XCD slicing: r9 showed 8x-redundant fetch) with 8
// independent atomic chains per thread (r9 showed 1 chain/thread is
// atomic-latency-bound: 90us vs 64us). Best of both structures.
__global__ __launch_bounds__(256) void scatter_gemm1_k(
        const int* __restrict__ ei, const float* __restrict__ ew,
        int* __restrict__ deg, unsigned* __restrict__ bucket,
        uint2* __restrict__ ovf, int* __restrict__ ovf_cnt,
        float* __restrict__ mean_acc,
        const float* __restrict__ We1, const float* __restrict__ ae1,
        const float* __restrict__ We2, const float* __restrict__ ae2,
        const float* __restrict__ We3, const float* __restrict__ ae3,
        float* __restrict__ ce,
        const float* __restrict__ X, const float* __restrict__ W,
        const float* __restrict__ as_, const float* __restrict__ ad_,
        unsigned short* __restrict__ H, float* __restrict__ Asrc,
        float* __restrict__ Adst) {
    extern __shared__ float smem[];
    const int tid = threadIdx.x;

    if (blockIdx.x < SGRID) {
        // ---------------- scatter path: 8 edges / thread, one pass ----------------
        int base = blockIdx.x * EPB;
        int off0 = base + (tid << 2);
        int off1 = off0 + 1024;
        const int* dstp = ei + N_EDGES;
        int4 d0 = make_int4(-1, -1, -1, -1), d1 = make_int4(-1, -1, -1, -1);
        int4 s0e = make_int4(0, 0, 0, 0),   s1e = make_int4(0, 0, 0, 0);
        float4 w0 = {0, 0, 0, 0}, w1 = {0, 0, 0, 0};
        if (off0 < N_EDGES) {
            d0 = *(const int4*)(dstp + off0);
            s0e = *(const int4*)(ei + off0);
            w0 = *(const float4*)(ew + off0);
        }
        if (off1 < N_EDGES) {
            d1 = *(const int4*)(dstp + off1);
            s1e = *(const int4*)(ei + off1);
            w1 = *(const float4*)(ew + off1);
        }

        float s = w0.x + w0.y + w0.z + w0.w + w1.x + w1.y + w1.z + w1.w;

        const int dv[8] = {d0.x, d0.y, d0.z, d0.w, d1.x, d1.y, d1.z, d1.w};
        const int sv[8] = {s0e.x, s0e.y, s0e.z, s0e.w, s1e.x, s1e.y, s1e.z, s1e.w};
        const float wvv[8] = {w0.x, w0.y, w0.z, w0.w, w1.x, w1.y, w1.z, w1.w};
        #pragma unroll
        for (int i = 0; i < 8; ++i) {
            int dst = dv[i];
            if (dst >= 0) {
                int pos = atomicAdd(&deg[dst], 1);
                unsigned entry = (unsigned)(sv[i] & 0xFFFF) | ((unsigned)f2bf(wvv[i]) << 16);
                if (pos < CAP) bucket[(dst << 6) + pos] = entry;
                else { int op = atomicAdd(ovf_cnt, 1); ovf[op] = make_uint2((unsigned)dst, entry); }
            }
        }

        int lane = tid & 63, wv = tid >> 6;
        s = wave_sum(s);
        if (lane == 0) smem[wv] = s;
        __syncthreads();
        if (tid == 0) atomicAdd(mean_acc, smem[0] + smem[1] + smem[2] + smem[3]);

        if (blockIdx.x == 0 && wv >= 1) {
            const float* We = (wv == 1) ? We1 : (wv == 2) ? We2 : We3;
            const float* ae = (wv == 1) ? ae1 : (wv == 2) ? ae2 : ae3;
            float v = We[lane] * ae[lane];
            v = wave_sum(v);
            if (lane == 0) ce[wv - 1] = v;
        }
        return;
    }

    // ---------------- gemm path (layer 1, F = 128) ----------------
    float* Xs = smem;              // 64*17 floats
    float* Wt = smem + 64 * 17;    // 16*64 floats (current k-tile)
    const int tx = tid & 15, ty = tid >> 4;
    const int bid = blockIdx.x - SGRID;
    const int rowBase = bid * 64;

    float4 acc0 = {0,0,0,0}, acc1 = {0,0,0,0}, acc2 = {0,0,0,0}, acc3 = {0,0,0,0};
    const int xrow = tid >> 2;
    const int xkq  = tid & 3;
    const float4* W4 = (const float4*)W;
    float4* Wt4 = (float4*)Wt;

    #pragma unroll 2
    for (int kt = 0; kt < (F_IN_DIM >> 4); ++kt) {
        __syncthreads();
        int k0 = kt << 4;
        int grow = rowBase + xrow;
        float4 xv = {0,0,0,0};
        if (grow < N_NODES)
            xv = *(const float4*)(X + (size_t)grow * F_IN_DIM + k0 + (xkq << 2));
        float* xd = Xs + xrow * 17 + (xkq << 2);
        xd[0] = xv.x; xd[1] = xv.y; xd[2] = xv.z; xd[3] = xv.w;
        Wt4[tid] = W4[(kt << 8) + tid];   // 16x64 tile, one float4/thread
        __syncthreads();

        #pragma unroll
        for (int kk = 0; kk < 16; ++kk) {
            float4 b = *(const float4*)&Wt[kk * HID + (tx << 2)];
            float a0 = Xs[(ty * 4 + 0) * 17 + kk];
            float a1 = Xs[(ty * 4 + 1) * 17 + kk];
            float a2 = Xs[(ty * 4 + 2) * 17 + kk];
            float a3 = Xs[(ty * 4 + 3) * 17 + kk];
            acc0.x += a0 * b.x; acc0.y += a0 * b.y; acc0.z += a0 * b.z; acc0.w += a0 * b.w;
            acc1.x += a1 * b.x; acc1.y += a1 * b.y; acc1.z += a1 * b.z; acc1.w += a1 * b.w;
            acc2.x += a2 * b.x; acc2.y += a2 * b.y; acc2.z += a2 * b.z; acc2.w += a2 * b.w;
            acc3.x += a3 * b.x; acc3.y += a3 * b.y; acc3.z += a3 * b.z; acc3.w += a3 * b.w;
        }
    }

    float4 as4 = *(const float4*)(as_ + (tx << 2));
    float4 ad4 = *(const float4*)(ad_ + (tx << 2));
    float4 accs[4] = {acc0, acc1, acc2, acc3};
    #pragma unroll
    for (int i = 0; i < 4; ++i) {
        int row = rowBase + ty * 4 + i;
        if (row >= N_NODES) break;
        float4 a = accs[i];
        ushort4 hv;
        hv.x = f2bf(a.x); hv.y = f2bf(a.y); hv.z = f2bf(a.z); hv.w = f2bf(a.w);
        *(ushort4*)(H + (size_t)row * HID + (tx << 2)) = hv;
        float vs = a.x * as4.x + a.y * as4.y + a.z * as4.z + a.w * as4.w;
        float vd = a.x * ad4.x + a.y * ad4.y + a.z * ad4.z + a.w * ad4.w;
        #pragma unroll
        for (int o = 8; o; o >>= 1) { vs += __shfl_xor(vs, o, 64); vd += __shfl_xor(vd, o, 64); }
        if (tx == 0) { Asrc[row] = vs; Adst[row] = vd; }
    }
}

#define GATHA(sv0, sv1)                                                         \
    a0 = *(const ushort4*)(H + (size_t)(sv0).x * HID + (qlane << 2));           \
    a1 = *(const ushort4*)(H + (size_t)(sv0).y * HID + (qlane << 2));           \
    a2 = *(const ushort4*)(H + (size_t)(sv0).z * HID + (qlane << 2));           \
    a3 = *(const ushort4*)(H + (size_t)(sv0).w * HID + (qlane << 2));           \
    a4 = *(const ushort4*)(H + (size_t)(sv1).x * HID + (qlane << 2));           \
    a5 = *(const ushort4*)(H + (size_t)(sv1).y * HID + (qlane << 2));           \
    a6 = *(const ushort4*)(H + (size_t)(sv1).z * HID + (qlane << 2));           \
    a7 = *(const ushort4*)(H + (size_t)(sv1).w * HID + (qlane << 2));

#define GATHB(sv0, sv1)                                                         \
    b0 = *(const ushort4*)(H + (size_t)(sv0).x * HID + (qlane << 2));           \
    b1 = *(const ushort4*)(H + (size_t)(sv0).y * HID + (qlane << 2));           \
    b2 = *(const ushort4*)(H + (size_t)(sv0).z * HID + (qlane << 2));           \
    b3 = *(const ushort4*)(H + (size_t)(sv0).w * HID + (qlane << 2));           \
    b4 = *(const ushort4*)(H + (size_t)(sv1).x * HID + (qlane << 2));           \
    b5 = *(const ushort4*)(H + (size_t)(sv1).y * HID + (qlane << 2));           \
    b6 = *(const ushort4*)(H + (size_t)(sv1).z * HID + (qlane << 2));           \
    b7 = *(const ushort4*)(H + (size_t)(sv1).w * HID + (qlane << 2));

#define ACCA(pv0, pv1, ACC)                                                     \
    ACC.x += (pv0).x*bf2f(a0.x) + (pv0).y*bf2f(a1.x) + (pv0).z*bf2f(a2.x) + (pv0).w*bf2f(a3.x) \
           + (pv1).x*bf2f(a4.x) + (pv1).y*bf2f(a5.x) + (pv1).z*bf2f(a6.x) + (pv1).w*bf2f(a7.x); \
    ACC.y += (pv0).x*bf2f(a0.y) + (pv0).y*bf2f(a1.y) + (pv0).z*bf2f(a2.y) + (pv0).w*bf2f(a3.y) \
           + (pv1).x*bf2f(a4.y) + (pv1).y*bf2f(a5.y) + (pv1).z*bf2f(a6.y) + (pv1).w*bf2f(a7.y); \
    ACC.z += (pv0).x*bf2f(a0.z) + (pv0).y*bf2f(a1.z) + (pv0).z*bf2f(a2.z) + (pv0).w*bf2f(a3.z) \
           + (pv1).x*bf2f(a4.z) + (pv1).y*bf2f(a5.z) + (pv1).z*bf2f(a6.z) + (pv1).w*bf2f(a7.z); \
    ACC.w += (pv0).x*bf2f(a0.w) + (pv0).y*bf2f(a1.w) + (pv0).z*bf2f(a2.w) + (pv0).w*bf2f(a3.w) \
           + (pv1).x*bf2f(a4.w) + (pv1).y*bf2f(a5.w) + (pv1).z*bf2f(a6.w) + (pv1).w*bf2f(a7.w);

// Aggregate phase: prefetch-overlapped pipeline (measured-best form).
#define AGG_PHASE(ACC, DENOM)                                                   \
    {                                                                           \
        float a_self = Asrc[n] + ad + c * mv;                                   \
        a_self = (a_self > 0.f) ? a_self : NEG * a_self;                        \
        p_self = __expf(a_self);                                                \
        if (deg <= CAP) {                                                       \
            unsigned eent[4];                                                   \
            _Pragma("unroll")                                                   \
            for (int t = 0; t < 4; ++t) {                                       \
                int j = qlane + (t << 4);                                       \
                unsigned e = (j < deg) ? bucket[start + j] : 0u;                \
                eent[t] = e;                                                    \
                ls[slot][j] = (int)(e & 0xFFFF);                                \
            }                                                                   \
            __builtin_amdgcn_wave_barrier();                                    \
            int4 sA0 = *(int4*)&ls[slot][0];                                    \
            int4 sA1 = *(int4*)&ls[slot][4];                                    \
            ushort4 a0, a1, a2, a3, a4, a5, a6, a7;                             \
            ushort4 b0, b1, b2, b3, b4, b5, b6, b7;                             \
            GATHA(sA0, sA1)                       /* chunk 0 in flight */       \
            rr = *(const ushort4*)(H + (size_t)n * HID + (qlane << 2));         \
            float lsum = 0.f;                                                   \
            _Pragma("unroll")                                                   \
            for (int t = 0; t < 4; ++t) {                                       \
                int j = qlane + (t << 4);                                       \
                float p = 0.f;                                                  \
                if (j < deg) {                                                  \
                    int s = (int)(eent[t] & 0xFFFF);                            \
                    float a = Asrc[s] + ad + c * bf2f((unsigned short)(eent[t] >> 16)); \
                    a = (a > 0.f) ? a : NEG * a;                                \
                    p = __expf(a);                                              \
                    lsum += p;                                                  \
                }                                                               \
                lp[slot][j] = p;                                                \
            }                                                                   \
            if (qlane == 0) lsum += p_self;                                     \
            _Pragma("unroll")                                                   \
            for (int o = 1; o < 16; o <<= 1) lsum += __shfl_xor(lsum, o, 64);   \
            DENOM = lsum;                                                       \
            __builtin_amdgcn_wave_barrier();                                    \
            int dpad = (deg + 7) & ~7;                                          \
            for (int j = 0; j < dpad; j += 8) {                                 \
                int jn = (j + 8 < dpad) ? j + 8 : j;                            \
                int4 t0 = *(int4*)&ls[slot][jn];                                \
                int4 t1 = *(int4*)&ls[slot][jn + 4];                            \
                GATHB(t0, t1)                     /* next chunk in flight */    \
                float4 p0 = *(float4*)&lp[slot][j];                             \
                float4 p1 = *(float4*)&lp[slot][j + 4];                         \
                ACCA(p0, p1, ACC)                                               \
                a0 = b0; a1 = b1; a2 = b2; a3 = b3;                             \
                a4 = b4; a5 = b5; a6 = b6; a7 = b7;                             \
            }                                                                   \
        } else {                                                                \
            int novf = *ovf_cnt_p;                                              \
            float lsum = 0.f;                                                   \
            _Pragma("unroll")                                                   \
            for (int t = 0; t < 4; ++t) {                                       \
                int j = qlane + (t << 4);                                       \
                unsigned e = bucket[start + j];                                 \
                int s = e & 0xFFFF;                                             \
                float a = Asrc[s] + ad + c * bf2f((unsigned short)(e >> 16));   \
                a = (a > 0.f) ? a : NEG * a;                                    \
                float p = __expf(a);                                            \
                lsum += p;                                                      \
                lp[slot][j] = p;                                                \
                ls[slot][j] = s;                                                \
            }                                                                   \
            __builtin_amdgcn_wave_barrier();                                    \
            ushort4 a0, a1, a2, a3, a4, a5, a6, a7;                             \
            for (int j = 0; j < 64; j += 8) {                                   \
                float4 p0 = *(float4*)&lp[slot][j];                             \
                float4 p1 = *(float4*)&lp[slot][j + 4];                         \
                int4 s0 = *(int4*)&ls[slot][j];                                 \
                int4 s1 = *(int4*)&ls[slot][j + 4];                             \
                GATHA(s0, s1)                                                   \
                ACCA(p0, p1, ACC)                                               \
            }                                                                   \
            for (int i = 0; i < novf; ++i) {                                    \
                uint2 o = ovf[i];                                               \
                if ((int)o.x == n) {                                            \
                    unsigned e = o.y;                                           \
                    int s = e & 0xFFFF;                                         \
                    float a = Asrc[s] + ad + c * bf2f((unsigned short)(e >> 16));\
                    a = (a > 0.f) ? a : NEG * a;                                \
                    float p = __expf(a);                                        \
                    if (qlane == 0) lsum += p;                                  \
                    ushort4 r = *(const ushort4*)(H + (size_t)s * HID + (qlane << 2)); \
                    ACC.x += p * bf2f(r.x); ACC.y += p * bf2f(r.y);             \
                    ACC.z += p * bf2f(r.z); ACC.w += p * bf2f(r.w);             \
                }                                                               \
            }                                                                   \
            if (qlane == 0) lsum += p_self;                                     \
            _Pragma("unroll")                                                   \
            for (int o = 1; o < 16; o <<= 1) lsum += __shfl_xor(lsum, o, 64);   \
            DENOM = lsum;                                                       \
            rr = *(const ushort4*)(H + (size_t)n * HID + (qlane << 2));         \
        }                                                                       \
        ACC.x += p_self * bf2f(rr.x); ACC.y += p_self * bf2f(rr.y);             \
        ACC.z += p_self * bf2f(rr.z); ACC.w += p_self * bf2f(rr.w);             \
    }

// ---- FUSED aggregate (layer i) + relu + GEMM (layer i+1) + att dots ----
// Grid = 3125 blocks x 16 nodes: n < N_NODES always (no early return; barrier-safe).
__global__ __launch_bounds__(256) void agg_gemm_k(
        const unsigned short* __restrict__ H, const int* __restrict__ degArr,
        const unsigned* __restrict__ bucket,
        const uint2* __restrict__ ovf, const int* __restrict__ ovf_cnt_p,
        const float* __restrict__ Asrc, const float* __restrict__ Adst,
        const float* __restrict__ ceArr, int ci,
        const float* __restrict__ mean_acc,
        const float* __restrict__ bias,
        const float* __restrict__ Wn, const float* __restrict__ asn,
        const float* __restrict__ adn,
        unsigned short* __restrict__ H2, float* __restrict__ Asrc2,
        float* __restrict__ Adst2) {
    __shared__ float lp[16][64];
    __shared__ int   ls[16][64];
    __shared__ float Wl[64 * 64];      // 16 KB: next-layer weights
    __shared__ float rowBuf[16][68];   // padded rows (272 B stride, 16B-aligned)
    const int tid = threadIdx.x;
    int wv = tid >> 6, lane = tid & 63;
    int qid = lane >> 4, qlane = lane & 15;
    int slot = wv * 4 + qid;
    int n = blockIdx.x * 16 + slot;

    {   // stage next-layer W into LDS (covered by the syncthreads below)
        const float4* W4 = (const float4*)Wn;
        float4* Wl4 = (float4*)Wl;
        for (int i = tid; i < (HID * HID) >> 2; i += 256) Wl4[i] = W4[i];
    }

    int deg = degArr[n];
    int start = n << 6;
    float c = ceArr[ci];
    float ad = Adst[n];
    float mv = mean_acc[0] * (1.0f / (float)N_EDGES);
    float4 acc = {0, 0, 0, 0};
    float denom, p_self;
    ushort4 rr;

    AGG_PHASE(acc, denom)

    // bias + relu (fused layers always relu), stage row for gemm
    float inv = 1.f / (denom + 1e-16f);
    float4 b4 = *(const float4*)(bias + (qlane << 2));
    acc.x = fmaxf(acc.x * inv + b4.x, 0.f);
    acc.y = fmaxf(acc.y * inv + b4.y, 0.f);
    acc.z = fmaxf(acc.z * inv + b4.z, 0.f);
    acc.w = fmaxf(acc.w * inv + b4.w, 0.f);
    *(float4*)&rowBuf[slot][qlane << 2] = acc;
    __syncthreads();

    // gemm: h2[qlane*4..+3] = rowBuf[slot][:] @ Wl
    float4 h2 = {0, 0, 0, 0};
    #pragma unroll
    for (int k4 = 0; k4 < 16; ++k4) {
        float4 a4 = *(const float4*)&rowBuf[slot][k4 << 2];
        const float* wb = &Wl[(k4 << 2) * HID + (qlane << 2)];
        float4 w0 = *(const float4*)(wb);
        float4 w1 = *(const float4*)(wb + HID);
        float4 w2 = *(const float4*)(wb + 2 * HID);
        float4 w3 = *(const float4*)(wb + 3 * HID);
        h2.x += a4.x*w0.x + a4.y*w1.x + a4.z*w2.x + a4.w*w3.x;
        h2.y += a4.x*w0.y + a4.y*w1.y + a4.z*w2.y + a4.w*w3.y;
        h2.z += a4.x*w0.z + a4.y*w1.z + a4.z*w2.z + a4.w*w3.z;
        h2.w += a4.x*w0.w + a4.y*w1.w + a4.z*w2.w + a4.w*w3.w;
    }

    ushort4 hv;
    hv.x = f2bf(h2.x); hv.y = f2bf(h2.y); hv.z = f2bf(h2.z); hv.w = f2bf(h2.w);
    *(ushort4*)(H2 + (size_t)n * HID + (qlane << 2)) = hv;

    float4 as4 = *(const float4*)(asn + (qlane << 2));
    float4 ad4 = *(const float4*)(adn + (qlane << 2));
    float vs = h2.x * as4.x + h2.y * as4.y + h2.z * as4.z + h2.w * as4.w;
    float vd = h2.x * ad4.x + h2.y * ad4.y + h2.z * ad4.z + h2.w * ad4.w;
    #pragma unroll
    for (int o = 8; o; o >>= 1) { vs += __shfl_xor(vs, o, 64); vd += __shfl_xor(vd, o, 64); }
    if (qlane == 0) { Asrc2[n] = vs; Adst2[n] = vd; }
}

// ---- final aggregate (layer 3): emits per-node pooled-readout scalar ----
__global__ __launch_bounds__(256) void aggregate_scalar_k(
        const unsigned short* __restrict__ H, const int* __restrict__ degArr,
        const unsigned* __restrict__ bucket,
        const uint2* __restrict__ ovf, const int* __restrict__ ovf_cnt_p,
        const float* __restrict__ Asrc, const float* __restrict__ Adst,
        const float* __restrict__ ceArr, int ci,
        const float* __restrict__ mean_acc,
        const float* __restrict__ bias, const float* __restrict__ lin_w,
        float* __restrict__ Sout) {
    __shared__ float lp[16][64];
    __shared__ int   ls[16][64];
    int wv = threadIdx.x >> 6, lane = threadIdx.x & 63;
    int qid = lane >> 4, qlane = lane & 15;
    int slot = wv * 4 + qid;
    int n = blockIdx.x * 16 + slot;
    if (n >= N_NODES) return;
    int deg = degArr[n];
    int start = n << 6;
    float c = ceArr[ci];
    float ad = Adst[n];
    float mv = mean_acc[0] * (1.0f / (float)N_EDGES);
    float4 acc = {0, 0, 0, 0};
    float denom, p_self;
    ushort4 rr;

    AGG_PHASE(acc, denom)

    float inv = 1.f / (denom + 1e-16f);
    float4 b4 = *(const float4*)(bias + (qlane << 2));
    float4 lw = *(const float4*)(lin_w + (qlane << 2));
    float s = (acc.x * inv + b4.x) * lw.x
            + (acc.y * inv + b4.y) * lw.y
            + (acc.z * inv + b4.z) * lw.z
            + (acc.w * inv + b4.w) * lw.w;
    #pragma unroll
    for (int o = 8; o; o >>= 1) s += __shfl_xor(s, o, 64);
    if (qlane == 0) Sout[n] = s;
}

// ---- pool + readout over per-node scalars: one wave per group ----
__global__ __launch_bounds__(256) void pool_readout_k(
        const float* __restrict__ S, const int* __restrict__ batch,
        const float* __restrict__ lin_b, float* __restrict__ out) {
    int wv = threadIdx.x >> 6, lane = threadIdx.x & 63;
    int g = blockIdx.x * 4 + wv;
    if (g >= NG) return;
    int lo = 0, hi = N_NODES;
    while (lo < hi) { int m = (lo + hi) >> 1; if (batch[m] < g) lo = m + 1; else hi = m; }
    int start = lo;
    hi = N_NODES;
    while (lo < hi) { int m = (lo + hi) >> 1; if (batch[m] < g + 1) lo = m + 1; else hi = m; }
    int end = lo;
    float acc = 0.f;
    for (int n = start + lane; n < end; n += 64) acc += S[n];
    acc = wave_sum(acc);
    if (lane == 0) {
        float cntf = (float)(end - start);
        float z = acc / fmaxf(cntf, 1.f) + lin_b[0];
        out[g] = 1.f / (1.f + __expf(-z));
    }
}

extern "C" void kernel_launch(void* const* d_in, const int* in_sizes, int n_in,
                              void* d_out, int out_size, void* d_ws, size_t ws_size,
                              hipStream_t stream) {
    const float* x     = (const float*)d_in[0];
    const int*   ei    = (const int*)d_in[1];
    const float* ew    = (const float*)d_in[2];
    const int*   batch = (const int*)d_in[3];
    const float* W1  = (const float*)d_in[4];
    const float* as1 = (const float*)d_in[5];
    const float* ad1 = (const float*)d_in[6];
    const float* We1 = (const float*)d_in[7];
    const float* ae1 = (const float*)d_in[8];
    const float* b1  = (const float*)d_in[9];
    const float* W2  = (const float*)d_in[10];
    const float* as2 = (const float*)d_in[11];
    const float* ad2 = (const float*)d_in[12];
    const float* We2 = (const float*)d_in[13];
    const float* ae2 = (const float*)d_in[14];
    const float* b2  = (const float*)d_in[15];
    const float* W3  = (const float*)d_in[16];
    const float* as3 = (const float*)d_in[17];
    const float* ad3 = (const float*)d_in[18];
    const float* We3 = (const float*)d_in[19];
    const float* ae3 = (const float*)d_in[20];
    const float* b3  = (const float*)d_in[21];
    const float* lin_w = (const float*)d_in[22];
    const float* lin_b = (const float*)d_in[23];
    float* out = (float*)d_out;

    char* w = (char*)d_ws;
    size_t off = 0;
    auto alloc = [&](size_t bytes) -> void* {
        void* p = w + off;
        off = (off + bytes + 255) & ~(size_t)255;
        return p;
    };
    // zeroed region (memset each call; ws is poisoned)
    int*   deg      = (int*)alloc(N_NODES * sizeof(int));
    float* mean_acc = (float*)alloc(sizeof(float));
    int*   ovf_cnt  = (int*)alloc(sizeof(int));
    size_t zero_bytes = off;
    // non-zeroed
    float* ce      = (float*)alloc(4 * sizeof(float));
    unsigned* bucket = (unsigned*)alloc((size_t)N_NODES * CAP * sizeof(unsigned));
    uint2* ovf     = (uint2*)alloc((size_t)N_EDGES * sizeof(uint2));
    float* a_src   = (float*)alloc(N_NODES * sizeof(float));
    float* a_dst   = (float*)alloc(N_NODES * sizeof(float));
    float* a_src2  = (float*)alloc(N_NODES * sizeof(float));
    float* a_dst2  = (float*)alloc(N_NODES * sizeof(float));
    unsigned short* hbuf  = (unsigned short*)alloc((size_t)N_NODES * HID * sizeof(unsigned short));
    unsigned short* hbuf2 = (unsigned short*)alloc((size_t)N_NODES * HID * sizeof(unsigned short));
    float* Sbuf    = (float*)alloc(N_NODES * sizeof(float));

    hipMemsetAsync(d_ws, 0, zero_bytes, stream);

    int agrid = (N_NODES + 15) / 16;   // 3125 -> exactly 50000 nodes
    size_t lds_f = (size_t)(64 * 17 + 16 * 64) * sizeof(float);   // 8.4 KB

    // K1: bucket build + layer-1 GEMM (independent work, one launch)
    scatter_gemm1_k<<<SGRID + GGRID, 256, lds_f, stream>>>(
        ei, ew, deg, bucket, ovf, ovf_cnt, mean_acc,
        We1, ae1, We2, ae2, We3, ae3, ce,
        x, W1, as1, ad1, hbuf, a_src, a_dst);

    // K2: aggregate layer 1 + relu + GEMM layer 2 (H: hbuf -> hbuf2)
    agg_gemm_k<<<agrid, 256, 0, stream>>>(hbuf, deg, bucket, ovf, ovf_cnt,
                                          a_src, a_dst, ce, 0, mean_acc, b1,
                                          W2, as2, ad2, hbuf2, a_src2, a_dst2);

    // K3: aggregate layer 2 + relu + GEMM layer 3 (H: hbuf2 -> hbuf)
    agg_gemm_k<<<agrid, 256, 0, stream>>>(hbuf2, deg, bucket, ovf, ovf_cnt,
                                          a_src2, a_dst2, ce, 1, mean_acc, b2,
                                          W3, as3, ad3, hbuf, a_src, a_dst);

    // K4: aggregate layer 3, fold lin_w dot -> per-node scalar
    aggregate_scalar_k<<<agrid, 256, 0, stream>>>(hbuf, deg, bucket, ovf, ovf_cnt,
                                                  a_src, a_dst, ce, 2, mean_acc,
                                                  b3, lin_w, Sbuf);

    // K5: pool + readout over scalars
    pool_readout_k<<<NG / 4, 256, 0, stream>>>(Sbuf, batch, lin_b, out);
}